// Round 8
// baseline (950.154 us; speedup 1.0000x reference)
//
#include <hip/hip_runtime.h>

typedef unsigned short u16;
typedef unsigned int   u32;

#define Bv  16
#define Nv  512
#define Cv  512
#define NSv 16
#define CCv 64

// ---------------- kNN: mirror XLA fp32 — dot = fma-chain (GEMM K-loop), sq = seq no-fma ----
// d = (sq_n + sq_m) - 2*dot, stable lower-index ties (lax.top_k semantics).
__global__ __launch_bounds__(512) void knn_kernel(const float* __restrict__ p,
                                                  int* __restrict__ idx_out) {
#pragma clang fp contract(off)
  __shared__ float px[Nv], py[Nv], pz[Nv], sq[Nv];
  const int b = blockIdx.x;
  const int t = threadIdx.x;
  {
    float x = p[(b * Nv + t) * 3 + 0];
    float y = p[(b * Nv + t) * 3 + 1];
    float z = p[(b * Nv + t) * 3 + 2];
    px[t] = x; py[t] = y; pz[t] = z;
    sq[t] = ((x * x) + (y * y)) + (z * z);   // jnp.sum(p*p,-1): mul then sequential add
  }
  __syncthreads();
  const float qx = px[t], qy = py[t], qz = pz[t], qs = sq[t];
  float bd[NSv];
  int bi[NSv];
#pragma unroll
  for (int i = 0; i < NSv; i++) { bd[i] = 1e30f; bi[i] = 0; }
  for (int m = 0; m < Nv; m++) {
    // XLA/Eigen GEMM K-loop: acc = fma(a_k, b_k, acc), seeded with fl(x*x')
    float dot = __builtin_fmaf(qz, pz[m], __builtin_fmaf(qy, py[m], qx * px[m]));
    float d = (qs + sq[m]) - (2.0f * dot);   // reference expression order
    if (d < bd[NSv - 1]) {                   // strict <: lower index wins ties
      int pos = NSv - 1;
      while (pos > 0 && bd[pos - 1] > d) {   // strict >: stable among equals
        bd[pos] = bd[pos - 1]; bi[pos] = bi[pos - 1]; pos--;
      }
      bd[pos] = d; bi[pos] = m;
    }
  }
  int* o = idx_out + (b * Nv + t) * NSv;
#pragma unroll
  for (int i = 0; i < NSv; i++) o[i] = bi[i];
}

// ---------------- QKV GEMM: fp32 in, fp32 out ----------------
__device__ __forceinline__ void stage32x64f(const float* __restrict__ g, float (*lds)[64], int t) {
  const int kk = t >> 3, nn = (t & 7) * 8;
  const float4 a = *(const float4*)(g + kk * 512 + nn);
  const float4 b = *(const float4*)(g + kk * 512 + nn + 4);
  *(float4*)&lds[kk][nn] = a;
  *(float4*)&lds[kk][nn + 4] = b;
}

__global__ __launch_bounds__(256) void qkv_gemm(
    const float* __restrict__ x,
    const float* __restrict__ Wq, const float* __restrict__ bq,
    const float* __restrict__ Wk, const float* __restrict__ bk,
    const float* __restrict__ Wv, const float* __restrict__ bv,
    float* __restrict__ xq, float* __restrict__ xk, float* __restrict__ xv) {
  __shared__ float As[32][64];
  __shared__ float Bs[3][32][64];
  const int bm = blockIdx.x;           // b*8 + mtile
  const int b  = bm >> 3;
  const int m0 = (bm & 7) * 64;
  const int j0 = blockIdx.y * 64;
  const int t  = threadIdx.x;
  const int tx = t & 15, ty = t >> 4;
  float aq[4][4] = {}, ak[4][4] = {}, av[4][4] = {};
  const float* xb = x + b * 512 * 512;   // x[b][c][n]: rows contiguous in n
  for (int k0 = 0; k0 < 512; k0 += 32) {
    stage32x64f(xb + k0 * 512 + m0, As, t);
    stage32x64f(Wq + k0 * 512 + j0, Bs[0], t);
    stage32x64f(Wk + k0 * 512 + j0, Bs[1], t);
    stage32x64f(Wv + k0 * 512 + j0, Bs[2], t);
    __syncthreads();
#pragma unroll 4
    for (int kk = 0; kk < 32; kk++) {
      const float4 a4 = *(const float4*)&As[kk][ty * 4];
      const float4 q4 = *(const float4*)&Bs[0][kk][tx * 4];
      const float4 k4 = *(const float4*)&Bs[1][kk][tx * 4];
      const float4 v4 = *(const float4*)&Bs[2][kk][tx * 4];
      const float a[4]  = {a4.x, a4.y, a4.z, a4.w};
      const float qr[4] = {q4.x, q4.y, q4.z, q4.w};
      const float kr[4] = {k4.x, k4.y, k4.z, k4.w};
      const float vr[4] = {v4.x, v4.y, v4.z, v4.w};
#pragma unroll
      for (int ii = 0; ii < 4; ii++)
#pragma unroll
        for (int i = 0; i < 4; i++) {
          aq[ii][i] = fmaf(a[ii], qr[i], aq[ii][i]);
          ak[ii][i] = fmaf(a[ii], kr[i], ak[ii][i]);
          av[ii][i] = fmaf(a[ii], vr[i], av[ii][i]);
        }
    }
    __syncthreads();
  }
  float bqr[4], bkr[4], bvr[4];
#pragma unroll
  for (int i = 0; i < 4; i++) {
    bqr[i] = bq[j0 + tx * 4 + i];
    bkr[i] = bk[j0 + tx * 4 + i];
    bvr[i] = bv[j0 + tx * 4 + i];
  }
#pragma unroll
  for (int ii = 0; ii < 4; ii++) {
    const int r = b * 512 + m0 + ty * 4 + ii;
    const int base = r * 512 + j0 + tx * 4;
    *(float4*)&xq[base] = make_float4(aq[ii][0] + bqr[0], aq[ii][1] + bqr[1],
                                      aq[ii][2] + bqr[2], aq[ii][3] + bqr[3]);
    *(float4*)&xk[base] = make_float4(ak[ii][0] + bkr[0], ak[ii][1] + bkr[1],
                                      ak[ii][2] + bkr[2], ak[ii][3] + bkr[3]);
    *(float4*)&xv[base] = make_float4(av[ii][0] + bvr[0], av[ii][1] + bvr[1],
                                      av[ii][2] + bvr[2], av[ii][3] + bvr[3]);
  }
}

// ---------------- fused attention: one block per (b,n) ----------------
#define USP 516
#define WSP 68

__global__ __launch_bounds__(256) void attn_kernel(
    const float* __restrict__ p, const int* __restrict__ idx,
    const float* __restrict__ xq, const float* __restrict__ xk, const float* __restrict__ xv,
    const float* __restrict__ p1W, const float* __restrict__ p1b,
    const float* __restrict__ pbg, const float* __restrict__ pbb,
    const float* __restrict__ p2W, const float* __restrict__ p2b,
    const float* __restrict__ bn1g, const float* __restrict__ bn1b,
    const float* __restrict__ w1W, const float* __restrict__ w1b,
    const float* __restrict__ bn2g, const float* __restrict__ bn2b,
    const float* __restrict__ w2W, const float* __restrict__ w2b,
    float* __restrict__ out) {
  const float rno = 1.0f / sqrtf(1.0f + 1e-5f);
  const int n = blockIdx.x, b = blockIdx.y;
  const int t = threadIdx.x;
  const int row = b * Nv + n;
  __shared__ float u_s[NSv][USP];
  __shared__ float w1f[64][WSP];
  __shared__ float w2f[64][WSP];
  __shared__ float h_s[NSv][3];
  __shared__ float r1_s[NSv][WSP];
  __shared__ float sm_s[NSv][WSP];
  __shared__ int   idx_s[NSv];

  if (t < NSv) idx_s[t] = idx[row * NSv + t] & (Nv - 1);
  // stage w2 (64x64 fp32) once
  {
    const int r = t >> 2, cp = (t & 3) * 16;
#pragma unroll
    for (int j = 0; j < 16; j++) w2f[r][cp + j] = w2W[r * 64 + cp + j];
  }
  __syncthreads();

  // h[k][j] = relu(bn_p(p_r @ p1W + p1b))   (16x3, 48 threads)
  if (t < 48) {
    const int k = t / 3, j = t % 3;
    const int m = idx_s[k];
    float d0 = p[(b * Nv + m) * 3 + 0] - p[(b * Nv + n) * 3 + 0];
    float d1 = p[(b * Nv + m) * 3 + 1] - p[(b * Nv + n) * 3 + 1];
    float d2 = p[(b * Nv + m) * 3 + 2] - p[(b * Nv + n) * 3 + 2];
    float y = d0 * p1W[0 * 3 + j] + d1 * p1W[1 * 3 + j] + d2 * p1W[2 * 3 + j] + p1b[j];
    y = y * (pbg[j] * rno) + pbb[j];
    h_s[k][j] = fmaxf(y, 0.0f);
  }
  __syncthreads();

  // per-thread channel pair
  const int c0 = t, c1 = t + 256;
  const float pw00 = p2W[c0],        pw01 = p2W[c1];
  const float pw10 = p2W[512 + c0],  pw11 = p2W[512 + c1];
  const float pw20 = p2W[1024 + c0], pw21 = p2W[1024 + c1];
  const float pb0  = p2b[c0],        pb1  = p2b[c1];

  // u[k][c] = relu(bn1(xk_g - xq + pr))
  {
    const float q0 = xq[row * Cv + c0], q1 = xq[row * Cv + c1];
    const float s10 = bn1g[c0] * rno, s11 = bn1g[c1] * rno;
    const float b10 = bn1b[c0], b11 = bn1b[c1];
#pragma unroll
    for (int k = 0; k < NSv; k++) {
      const float* xkr = xk + (b * Nv + idx_s[k]) * Cv;
      const float h0 = h_s[k][0], h1 = h_s[k][1], h2 = h_s[k][2];
      float pr0 = h0 * pw00 + h1 * pw10 + h2 * pw20 + pb0;
      float pr1 = h0 * pw01 + h1 * pw11 + h2 * pw21 + pb1;
      float w0 = (xkr[c0] - q0 + pr0) * s10 + b10;
      float w1v = (xkr[c1] - q1 + pr1) * s11 + b11;
      u_s[k][c0] = fmaxf(w0, 0.0f);
      u_s[k][c1] = fmaxf(w1v, 0.0f);
    }
  }
  __syncthreads();

  // t1 = u(16x512) @ w1W(512x64), +w1b, bn2, relu -> r1_s
  {
    const int k = t >> 4, cc0 = (t & 15) * 4;
    float acc0 = 0.f, acc1 = 0.f, acc2 = 0.f, acc3 = 0.f;
    for (int kc = 0; kc < Cv; kc += 64) {
      {
        const int r = t >> 2, cp = (t & 3) * 16;
#pragma unroll
        for (int j = 0; j < 16; j++) w1f[r][cp + j] = w1W[(kc + r) * 64 + cp + j];
      }
      __syncthreads();
#pragma unroll 8
      for (int c = 0; c < 64; c++) {
        const float uv = u_s[k][kc + c];
        const float4 w4 = *(const float4*)&w1f[c][cc0];
        acc0 = fmaf(uv, w4.x, acc0);
        acc1 = fmaf(uv, w4.y, acc1);
        acc2 = fmaf(uv, w4.z, acc2);
        acc3 = fmaf(uv, w4.w, acc3);
      }
      __syncthreads();
    }
    const float a[4] = {acc0, acc1, acc2, acc3};
#pragma unroll
    for (int i = 0; i < 4; i++) {
      const int cc = cc0 + i;
      float v = (a[i] + w1b[cc]) * (bn2g[cc] * rno) + bn2b[cc];
      r1_s[k][cc] = fmaxf(v, 0.0f);
    }
  }
  __syncthreads();

  // t2 = r1(16x64) @ w2(64x64) + w2b -> logits
  {
    const int k = t >> 4, cc0 = (t & 15) * 4;
    float acc0 = 0.f, acc1 = 0.f, acc2 = 0.f, acc3 = 0.f;
#pragma unroll 8
    for (int c = 0; c < 64; c++) {
      const float rv = r1_s[k][c];
      const float4 w4 = *(const float4*)&w2f[c][cc0];
      acc0 = fmaf(rv, w4.x, acc0);
      acc1 = fmaf(rv, w4.y, acc1);
      acc2 = fmaf(rv, w4.z, acc2);
      acc3 = fmaf(rv, w4.w, acc3);
    }
    sm_s[k][cc0 + 0] = acc0 + w2b[cc0 + 0];
    sm_s[k][cc0 + 1] = acc1 + w2b[cc0 + 1];
    sm_s[k][cc0 + 2] = acc2 + w2b[cc0 + 2];
    sm_s[k][cc0 + 3] = acc3 + w2b[cc0 + 3];
  }
  __syncthreads();

  // softmax over the 16 neighbors, per channel
  if (t < CCv) {
    float v[NSv];
#pragma unroll
    for (int k = 0; k < NSv; k++) v[k] = sm_s[k][t];
    float mx = v[0];
#pragma unroll
    for (int k = 1; k < NSv; k++) mx = fmaxf(mx, v[k]);
    float s = 0.0f;
#pragma unroll
    for (int k = 0; k < NSv; k++) { v[k] = expf(v[k] - mx); s += v[k]; }
    const float is = 1.0f / s;
#pragma unroll
    for (int k = 0; k < NSv; k++) sm_s[k][t] = v[k] * is;
  }
  __syncthreads();

  // out[c] = sum_k (xv_g + pr) * sm[k][c & 63]
  {
    const int cc0 = c0 & 63, cc1 = c1 & 63;
    float acc0 = 0.f, acc1 = 0.f;
#pragma unroll
    for (int k = 0; k < NSv; k++) {
      const float* xvr = xv + (b * Nv + idx_s[k]) * Cv;
      const float h0 = h_s[k][0], h1 = h_s[k][1], h2 = h_s[k][2];
      float pr0 = h0 * pw00 + h1 * pw10 + h2 * pw20 + pb0;
      float pr1 = h0 * pw01 + h1 * pw11 + h2 * pw21 + pb1;
      acc0 += (xvr[c0] + pr0) * sm_s[k][cc0];
      acc1 += (xvr[c1] + pr1) * sm_s[k][cc1];
    }
    out[row * Cv + c0] = acc0;
    out[row * Cv + c1] = acc1;
  }
}

extern "C" void kernel_launch(void* const* d_in, const int* in_sizes, int n_in,
                              void* d_out, int out_size, void* d_ws, size_t ws_size,
                              hipStream_t stream) {
  const float* p    = (const float*)d_in[0];
  const float* x    = (const float*)d_in[1];
  const float* Wq   = (const float*)d_in[2];
  const float* bq   = (const float*)d_in[3];
  const float* Wk   = (const float*)d_in[4];
  const float* bk   = (const float*)d_in[5];
  const float* Wv   = (const float*)d_in[6];
  const float* bv   = (const float*)d_in[7];
  const float* p1W  = (const float*)d_in[8];
  const float* p1b  = (const float*)d_in[9];
  const float* pbg  = (const float*)d_in[10];
  const float* pbb  = (const float*)d_in[11];
  const float* p2W  = (const float*)d_in[12];
  const float* p2b  = (const float*)d_in[13];
  const float* bn1g = (const float*)d_in[14];
  const float* bn1b = (const float*)d_in[15];
  const float* w1W  = (const float*)d_in[16];
  const float* w1b  = (const float*)d_in[17];
  const float* bn2g = (const float*)d_in[18];
  const float* bn2b = (const float*)d_in[19];
  const float* w2W  = (const float*)d_in[20];
  const float* w2b  = (const float*)d_in[21];

  // ws layout (bytes): idx int [0, 524288) | xq/xk/xv fp32, 16 MiB each -> total ~48.5 MiB
  int*   idxb = (int*)d_ws;
  float* xq   = (float*)((char*)d_ws + 524288);
  float* xk   = xq + 8192 * 512;
  float* xv   = xk + 8192 * 512;

  knn_kernel<<<Bv, 512, 0, stream>>>(p, idxb);
  qkv_gemm<<<dim3(128, 8), 256, 0, stream>>>(x, Wq, bq, Wk, bk, Wv, bv, xq, xk, xv);
  attn_kernel<<<dim3(Nv, Bv), 256, 0, stream>>>(p, idxb, xq, xk, xv,
                                                p1W, p1b, pbg, pbb, p2W, p2b,
                                                bn1g, bn1b, w1W, w1b, bn2g, bn2b,
                                                w2W, w2b, (float*)d_out);
}

// Round 9
// 618.628 us; speedup vs baseline: 1.5359x; 1.5359x over previous
//
#include <hip/hip_runtime.h>

typedef unsigned short u16;
typedef unsigned int   u32;

#define Bv  16
#define Nv  512
#define Cv  512
#define NSv 16
#define CCv 64

// ---------------- kNN: register-resident compare-exchange top-16 ----------------
// Arithmetic bit-identical to round 8 (PASS): dot = fma-chain, d = (sq_n+sq_m) - 2*dot,
// strict > shifts (lower index wins ties). 4 threads/query x 128 candidates, then a
// stable 4-list merge (lists are ascending index ranges, processed in order).
__global__ __launch_bounds__(256) void knn_kernel(const float* __restrict__ p,
                                                  int* __restrict__ idx_out) {
#pragma clang fp contract(off)
  __shared__ float4 pnts[Nv];       // x, y, z, sq
  __shared__ float  ld[64][65];     // 64 queries x (4 lists x 16) +pad
  __shared__ int    li[64][65];
  const int b  = blockIdx.y;
  const int q0 = blockIdx.x * 64;
  const int t  = threadIdx.x;
  for (int e = t; e < Nv; e += 256) {
    float x = p[(b * Nv + e) * 3 + 0];
    float y = p[(b * Nv + e) * 3 + 1];
    float z = p[(b * Nv + e) * 3 + 2];
    float s = ((x * x) + (y * y)) + (z * z);   // jnp.sum(p*p,-1): seq, no fma
    pnts[e] = make_float4(x, y, z, s);
  }
  __syncthreads();

  // phase 1: thread (ql, r) scans candidates [r*128, r*128+128) for query q0+ql
  {
    const int ql = t >> 2, r = t & 3;
    const float4 q = pnts[q0 + ql];
    float bd[NSv]; int bi[NSv];
#pragma unroll
    for (int i = 0; i < NSv; i++) { bd[i] = 1e30f; bi[i] = 0; }
    const int m0 = r * 128;
#pragma unroll 1
    for (int i = 0; i < 128; i++) {
      const int m = m0 + i;
      const float4 c = pnts[m];
      float dot = __builtin_fmaf(q.z, c.z, __builtin_fmaf(q.y, c.y, q.x * c.x));
      float d = (q.w + c.w) - (2.0f * dot);
      bool cm[NSv];
#pragma unroll
      for (int j = 0; j < NSv; j++) cm[j] = bd[j] > d;   // strict: stable ties
#pragma unroll
      for (int j = NSv - 1; j > 0; j--) {
        bd[j] = cm[j - 1] ? bd[j - 1] : (cm[j] ? d : bd[j]);
        bi[j] = cm[j - 1] ? bi[j - 1] : (cm[j] ? m : bi[j]);
      }
      bd[0] = cm[0] ? d : bd[0];
      bi[0] = cm[0] ? m : bi[0];
    }
#pragma unroll
    for (int j = 0; j < NSv; j++) { ld[ql][r * 16 + j] = bd[j]; li[ql][r * 16 + j] = bi[j]; }
  }
  __syncthreads();

  // phase 2: lane t (<64) merges query t's 4 sorted lists, in ascending index order
  if (t < 64) {
    float bd[NSv]; int bi[NSv];
#pragma unroll
    for (int i = 0; i < NSv; i++) { bd[i] = 1e30f; bi[i] = 0; }
#pragma unroll 1
    for (int e = 0; e < 64; e++) {
      float d = ld[t][e];
      int   m = li[t][e];
      bool cm[NSv];
#pragma unroll
      for (int j = 0; j < NSv; j++) cm[j] = bd[j] > d;
#pragma unroll
      for (int j = NSv - 1; j > 0; j--) {
        bd[j] = cm[j - 1] ? bd[j - 1] : (cm[j] ? d : bd[j]);
        bi[j] = cm[j - 1] ? bi[j - 1] : (cm[j] ? m : bi[j]);
      }
      bd[0] = cm[0] ? d : bd[0];
      bi[0] = cm[0] ? m : bi[0];
    }
    int* o = idx_out + (b * Nv + q0 + t) * NSv;
#pragma unroll
    for (int j = 0; j < NSv; j++) o[j] = bi[j];
  }
}

// ---------------- QKV GEMM: fp32 in, fp32 out (unchanged from round 8) ----------------
__device__ __forceinline__ void stage32x64f(const float* __restrict__ g, float (*lds)[64], int t) {
  const int kk = t >> 3, nn = (t & 7) * 8;
  const float4 a = *(const float4*)(g + kk * 512 + nn);
  const float4 b = *(const float4*)(g + kk * 512 + nn + 4);
  *(float4*)&lds[kk][nn] = a;
  *(float4*)&lds[kk][nn + 4] = b;
}

__global__ __launch_bounds__(256) void qkv_gemm(
    const float* __restrict__ x,
    const float* __restrict__ Wq, const float* __restrict__ bq,
    const float* __restrict__ Wk, const float* __restrict__ bk,
    const float* __restrict__ Wv, const float* __restrict__ bv,
    float* __restrict__ xq, float* __restrict__ xk, float* __restrict__ xv) {
  __shared__ float As[32][64];
  __shared__ float Bs[3][32][64];
  const int bm = blockIdx.x;           // b*8 + mtile
  const int b  = bm >> 3;
  const int m0 = (bm & 7) * 64;
  const int j0 = blockIdx.y * 64;
  const int t  = threadIdx.x;
  const int tx = t & 15, ty = t >> 4;
  float aq[4][4] = {}, ak[4][4] = {}, av[4][4] = {};
  const float* xb = x + b * 512 * 512;   // x[b][c][n]: rows contiguous in n
  for (int k0 = 0; k0 < 512; k0 += 32) {
    stage32x64f(xb + k0 * 512 + m0, As, t);
    stage32x64f(Wq + k0 * 512 + j0, Bs[0], t);
    stage32x64f(Wk + k0 * 512 + j0, Bs[1], t);
    stage32x64f(Wv + k0 * 512 + j0, Bs[2], t);
    __syncthreads();
#pragma unroll 4
    for (int kk = 0; kk < 32; kk++) {
      const float4 a4 = *(const float4*)&As[kk][ty * 4];
      const float4 q4 = *(const float4*)&Bs[0][kk][tx * 4];
      const float4 k4 = *(const float4*)&Bs[1][kk][tx * 4];
      const float4 v4 = *(const float4*)&Bs[2][kk][tx * 4];
      const float a[4]  = {a4.x, a4.y, a4.z, a4.w};
      const float qr[4] = {q4.x, q4.y, q4.z, q4.w};
      const float kr[4] = {k4.x, k4.y, k4.z, k4.w};
      const float vr[4] = {v4.x, v4.y, v4.z, v4.w};
#pragma unroll
      for (int ii = 0; ii < 4; ii++)
#pragma unroll
        for (int i = 0; i < 4; i++) {
          aq[ii][i] = fmaf(a[ii], qr[i], aq[ii][i]);
          ak[ii][i] = fmaf(a[ii], kr[i], ak[ii][i]);
          av[ii][i] = fmaf(a[ii], vr[i], av[ii][i]);
        }
    }
    __syncthreads();
  }
  float bqr[4], bkr[4], bvr[4];
#pragma unroll
  for (int i = 0; i < 4; i++) {
    bqr[i] = bq[j0 + tx * 4 + i];
    bkr[i] = bk[j0 + tx * 4 + i];
    bvr[i] = bv[j0 + tx * 4 + i];
  }
#pragma unroll
  for (int ii = 0; ii < 4; ii++) {
    const int r = b * 512 + m0 + ty * 4 + ii;
    const int base = r * 512 + j0 + tx * 4;
    *(float4*)&xq[base] = make_float4(aq[ii][0] + bqr[0], aq[ii][1] + bqr[1],
                                      aq[ii][2] + bqr[2], aq[ii][3] + bqr[3]);
    *(float4*)&xk[base] = make_float4(ak[ii][0] + bkr[0], ak[ii][1] + bkr[1],
                                      ak[ii][2] + bkr[2], ak[ii][3] + bkr[3]);
    *(float4*)&xv[base] = make_float4(av[ii][0] + bvr[0], av[ii][1] + bvr[1],
                                      av[ii][2] + bvr[2], av[ii][3] + bvr[3]);
  }
}

// ---------------- fused attention: one block per (b,n) (unchanged from round 8) ------------
#define USP 516
#define WSP 68

__global__ __launch_bounds__(256) void attn_kernel(
    const float* __restrict__ p, const int* __restrict__ idx,
    const float* __restrict__ xq, const float* __restrict__ xk, const float* __restrict__ xv,
    const float* __restrict__ p1W, const float* __restrict__ p1b,
    const float* __restrict__ pbg, const float* __restrict__ pbb,
    const float* __restrict__ p2W, const float* __restrict__ p2b,
    const float* __restrict__ bn1g, const float* __restrict__ bn1b,
    const float* __restrict__ w1W, const float* __restrict__ w1b,
    const float* __restrict__ bn2g, const float* __restrict__ bn2b,
    const float* __restrict__ w2W, const float* __restrict__ w2b,
    float* __restrict__ out) {
  const float rno = 1.0f / sqrtf(1.0f + 1e-5f);
  const int n = blockIdx.x, b = blockIdx.y;
  const int t = threadIdx.x;
  const int row = b * Nv + n;
  __shared__ float u_s[NSv][USP];
  __shared__ float w1f[64][WSP];
  __shared__ float w2f[64][WSP];
  __shared__ float h_s[NSv][3];
  __shared__ float r1_s[NSv][WSP];
  __shared__ float sm_s[NSv][WSP];
  __shared__ int   idx_s[NSv];

  if (t < NSv) idx_s[t] = idx[row * NSv + t] & (Nv - 1);
  // stage w2 (64x64 fp32) once
  {
    const int r = t >> 2, cp = (t & 3) * 16;
#pragma unroll
    for (int j = 0; j < 16; j++) w2f[r][cp + j] = w2W[r * 64 + cp + j];
  }
  __syncthreads();

  // h[k][j] = relu(bn_p(p_r @ p1W + p1b))   (16x3, 48 threads)
  if (t < 48) {
    const int k = t / 3, j = t % 3;
    const int m = idx_s[k];
    float d0 = p[(b * Nv + m) * 3 + 0] - p[(b * Nv + n) * 3 + 0];
    float d1 = p[(b * Nv + m) * 3 + 1] - p[(b * Nv + n) * 3 + 1];
    float d2 = p[(b * Nv + m) * 3 + 2] - p[(b * Nv + n) * 3 + 2];
    float y = d0 * p1W[0 * 3 + j] + d1 * p1W[1 * 3 + j] + d2 * p1W[2 * 3 + j] + p1b[j];
    y = y * (pbg[j] * rno) + pbb[j];
    h_s[k][j] = fmaxf(y, 0.0f);
  }
  __syncthreads();

  // per-thread channel pair
  const int c0 = t, c1 = t + 256;
  const float pw00 = p2W[c0],        pw01 = p2W[c1];
  const float pw10 = p2W[512 + c0],  pw11 = p2W[512 + c1];
  const float pw20 = p2W[1024 + c0], pw21 = p2W[1024 + c1];
  const float pb0  = p2b[c0],        pb1  = p2b[c1];

  // u[k][c] = relu(bn1(xk_g - xq + pr))
  {
    const float q0 = xq[row * Cv + c0], q1 = xq[row * Cv + c1];
    const float s10 = bn1g[c0] * rno, s11 = bn1g[c1] * rno;
    const float b10 = bn1b[c0], b11 = bn1b[c1];
#pragma unroll
    for (int k = 0; k < NSv; k++) {
      const float* xkr = xk + (b * Nv + idx_s[k]) * Cv;
      const float h0 = h_s[k][0], h1 = h_s[k][1], h2 = h_s[k][2];
      float pr0 = h0 * pw00 + h1 * pw10 + h2 * pw20 + pb0;
      float pr1 = h0 * pw01 + h1 * pw11 + h2 * pw21 + pb1;
      float w0 = (xkr[c0] - q0 + pr0) * s10 + b10;
      float w1v = (xkr[c1] - q1 + pr1) * s11 + b11;
      u_s[k][c0] = fmaxf(w0, 0.0f);
      u_s[k][c1] = fmaxf(w1v, 0.0f);
    }
  }
  __syncthreads();

  // t1 = u(16x512) @ w1W(512x64), +w1b, bn2, relu -> r1_s
  {
    const int k = t >> 4, cc0 = (t & 15) * 4;
    float acc0 = 0.f, acc1 = 0.f, acc2 = 0.f, acc3 = 0.f;
    for (int kc = 0; kc < Cv; kc += 64) {
      {
        const int r = t >> 2, cp = (t & 3) * 16;
#pragma unroll
        for (int j = 0; j < 16; j++) w1f[r][cp + j] = w1W[(kc + r) * 64 + cp + j];
      }
      __syncthreads();
#pragma unroll 8
      for (int c = 0; c < 64; c++) {
        const float uv = u_s[k][kc + c];
        const float4 w4 = *(const float4*)&w1f[c][cc0];
        acc0 = fmaf(uv, w4.x, acc0);
        acc1 = fmaf(uv, w4.y, acc1);
        acc2 = fmaf(uv, w4.z, acc2);
        acc3 = fmaf(uv, w4.w, acc3);
      }
      __syncthreads();
    }
    const float a[4] = {acc0, acc1, acc2, acc3};
#pragma unroll
    for (int i = 0; i < 4; i++) {
      const int cc = cc0 + i;
      float v = (a[i] + w1b[cc]) * (bn2g[cc] * rno) + bn2b[cc];
      r1_s[k][cc] = fmaxf(v, 0.0f);
    }
  }
  __syncthreads();

  // t2 = r1(16x64) @ w2(64x64) + w2b -> logits
  {
    const int k = t >> 4, cc0 = (t & 15) * 4;
    float acc0 = 0.f, acc1 = 0.f, acc2 = 0.f, acc3 = 0.f;
#pragma unroll 8
    for (int c = 0; c < 64; c++) {
      const float rv = r1_s[k][c];
      const float4 w4 = *(const float4*)&w2f[c][cc0];
      acc0 = fmaf(rv, w4.x, acc0);
      acc1 = fmaf(rv, w4.y, acc1);
      acc2 = fmaf(rv, w4.z, acc2);
      acc3 = fmaf(rv, w4.w, acc3);
    }
    sm_s[k][cc0 + 0] = acc0 + w2b[cc0 + 0];
    sm_s[k][cc0 + 1] = acc1 + w2b[cc0 + 1];
    sm_s[k][cc0 + 2] = acc2 + w2b[cc0 + 2];
    sm_s[k][cc0 + 3] = acc3 + w2b[cc0 + 3];
  }
  __syncthreads();

  // softmax over the 16 neighbors, per channel
  if (t < CCv) {
    float v[NSv];
#pragma unroll
    for (int k = 0; k < NSv; k++) v[k] = sm_s[k][t];
    float mx = v[0];
#pragma unroll
    for (int k = 1; k < NSv; k++) mx = fmaxf(mx, v[k]);
    float s = 0.0f;
#pragma unroll
    for (int k = 0; k < NSv; k++) { v[k] = expf(v[k] - mx); s += v[k]; }
    const float is = 1.0f / s;
#pragma unroll
    for (int k = 0; k < NSv; k++) sm_s[k][t] = v[k] * is;
  }
  __syncthreads();

  // out[c] = sum_k (xv_g + pr) * sm[k][c & 63]
  {
    const int cc0 = c0 & 63, cc1 = c1 & 63;
    float acc0 = 0.f, acc1 = 0.f;
#pragma unroll
    for (int k = 0; k < NSv; k++) {
      const float* xvr = xv + (b * Nv + idx_s[k]) * Cv;
      const float h0 = h_s[k][0], h1 = h_s[k][1], h2 = h_s[k][2];
      float pr0 = h0 * pw00 + h1 * pw10 + h2 * pw20 + pb0;
      float pr1 = h0 * pw01 + h1 * pw11 + h2 * pw21 + pb1;
      acc0 += (xvr[c0] + pr0) * sm_s[k][cc0];
      acc1 += (xvr[c1] + pr1) * sm_s[k][cc1];
    }
    out[row * Cv + c0] = acc0;
    out[row * Cv + c1] = acc1;
  }
}

extern "C" void kernel_launch(void* const* d_in, const int* in_sizes, int n_in,
                              void* d_out, int out_size, void* d_ws, size_t ws_size,
                              hipStream_t stream) {
  const float* p    = (const float*)d_in[0];
  const float* x    = (const float*)d_in[1];
  const float* Wq   = (const float*)d_in[2];
  const float* bq   = (const float*)d_in[3];
  const float* Wk   = (const float*)d_in[4];
  const float* bk   = (const float*)d_in[5];
  const float* Wv   = (const float*)d_in[6];
  const float* bv   = (const float*)d_in[7];
  const float* p1W  = (const float*)d_in[8];
  const float* p1b  = (const float*)d_in[9];
  const float* pbg  = (const float*)d_in[10];
  const float* pbb  = (const float*)d_in[11];
  const float* p2W  = (const float*)d_in[12];
  const float* p2b  = (const float*)d_in[13];
  const float* bn1g = (const float*)d_in[14];
  const float* bn1b = (const float*)d_in[15];
  const float* w1W  = (const float*)d_in[16];
  const float* w1b  = (const float*)d_in[17];
  const float* bn2g = (const float*)d_in[18];
  const float* bn2b = (const float*)d_in[19];
  const float* w2W  = (const float*)d_in[20];
  const float* w2b  = (const float*)d_in[21];

  // ws layout (bytes): idx int [0, 524288) | xq/xk/xv fp32, 16 MiB each -> total ~48.5 MiB
  int*   idxb = (int*)d_ws;
  float* xq   = (float*)((char*)d_ws + 524288);
  float* xk   = xq + 8192 * 512;
  float* xv   = xk + 8192 * 512;

  knn_kernel<<<dim3(8, 16), 256, 0, stream>>>(p, idxb);
  qkv_gemm<<<dim3(128, 8), 256, 0, stream>>>(x, Wq, bq, Wk, bk, Wv, bv, xq, xk, xv);
  attn_kernel<<<dim3(Nv, Bv), 256, 0, stream>>>(p, idxb, xq, xk, xv,
                                                p1W, p1b, pbg, pbb, p2W, p2b,
                                                bn1g, bn1b, w1W, w1b, bn2g, bn2b,
                                                w2W, w2b, (float*)d_out);
}

// Round 10
// 505.951 us; speedup vs baseline: 1.8780x; 1.2227x over previous
//
#include <hip/hip_runtime.h>

typedef unsigned short u16;
typedef unsigned int   u32;

#define Bv  16
#define Nv  512
#define Cv  512
#define NSv 16
#define CCv 64

// ---------------- kNN: register-resident compare-exchange top-16 (unchanged, PASS) ----------
__global__ __launch_bounds__(256) void knn_kernel(const float* __restrict__ p,
                                                  int* __restrict__ idx_out) {
#pragma clang fp contract(off)
  __shared__ float4 pnts[Nv];
  __shared__ float  ld[64][65];
  __shared__ int    li[64][65];
  const int b  = blockIdx.y;
  const int q0 = blockIdx.x * 64;
  const int t  = threadIdx.x;
  for (int e = t; e < Nv; e += 256) {
    float x = p[(b * Nv + e) * 3 + 0];
    float y = p[(b * Nv + e) * 3 + 1];
    float z = p[(b * Nv + e) * 3 + 2];
    float s = ((x * x) + (y * y)) + (z * z);
    pnts[e] = make_float4(x, y, z, s);
  }
  __syncthreads();
  {
    const int ql = t >> 2, r = t & 3;
    const float4 q = pnts[q0 + ql];
    float bd[NSv]; int bi[NSv];
#pragma unroll
    for (int i = 0; i < NSv; i++) { bd[i] = 1e30f; bi[i] = 0; }
    const int m0 = r * 128;
#pragma unroll 1
    for (int i = 0; i < 128; i++) {
      const int m = m0 + i;
      const float4 c = pnts[m];
      float dot = __builtin_fmaf(q.z, c.z, __builtin_fmaf(q.y, c.y, q.x * c.x));
      float d = (q.w + c.w) - (2.0f * dot);
      bool cm[NSv];
#pragma unroll
      for (int j = 0; j < NSv; j++) cm[j] = bd[j] > d;
#pragma unroll
      for (int j = NSv - 1; j > 0; j--) {
        bd[j] = cm[j - 1] ? bd[j - 1] : (cm[j] ? d : bd[j]);
        bi[j] = cm[j - 1] ? bi[j - 1] : (cm[j] ? m : bi[j]);
      }
      bd[0] = cm[0] ? d : bd[0];
      bi[0] = cm[0] ? m : bi[0];
    }
#pragma unroll
    for (int j = 0; j < NSv; j++) { ld[ql][r * 16 + j] = bd[j]; li[ql][r * 16 + j] = bi[j]; }
  }
  __syncthreads();
  if (t < 64) {
    float bd[NSv]; int bi[NSv];
#pragma unroll
    for (int i = 0; i < NSv; i++) { bd[i] = 1e30f; bi[i] = 0; }
#pragma unroll 1
    for (int e = 0; e < 64; e++) {
      float d = ld[t][e];
      int   m = li[t][e];
      bool cm[NSv];
#pragma unroll
      for (int j = 0; j < NSv; j++) cm[j] = bd[j] > d;
#pragma unroll
      for (int j = NSv - 1; j > 0; j--) {
        bd[j] = cm[j - 1] ? bd[j - 1] : (cm[j] ? d : bd[j]);
        bi[j] = cm[j - 1] ? bi[j - 1] : (cm[j] ? m : bi[j]);
      }
      bd[0] = cm[0] ? d : bd[0];
      bi[0] = cm[0] ? m : bi[0];
    }
    int* o = idx_out + (b * Nv + q0 + t) * NSv;
#pragma unroll
    for (int j = 0; j < NSv; j++) o[j] = bi[j];
  }
}

// ---------------- QKV GEMM (unchanged from round 9) ----------------
__device__ __forceinline__ void stage32x64f(const float* __restrict__ g, float (*lds)[64], int t) {
  const int kk = t >> 3, nn = (t & 7) * 8;
  const float4 a = *(const float4*)(g + kk * 512 + nn);
  const float4 b = *(const float4*)(g + kk * 512 + nn + 4);
  *(float4*)&lds[kk][nn] = a;
  *(float4*)&lds[kk][nn + 4] = b;
}

__global__ __launch_bounds__(256) void qkv_gemm(
    const float* __restrict__ x,
    const float* __restrict__ Wq, const float* __restrict__ bq,
    const float* __restrict__ Wk, const float* __restrict__ bk,
    const float* __restrict__ Wv, const float* __restrict__ bv,
    float* __restrict__ xq, float* __restrict__ xk, float* __restrict__ xv) {
  __shared__ float As[32][64];
  __shared__ float Bs[3][32][64];
  const int bm = blockIdx.x;
  const int b  = bm >> 3;
  const int m0 = (bm & 7) * 64;
  const int j0 = blockIdx.y * 64;
  const int t  = threadIdx.x;
  const int tx = t & 15, ty = t >> 4;
  float aq[4][4] = {}, ak[4][4] = {}, av[4][4] = {};
  const float* xb = x + b * 512 * 512;
  for (int k0 = 0; k0 < 512; k0 += 32) {
    stage32x64f(xb + k0 * 512 + m0, As, t);
    stage32x64f(Wq + k0 * 512 + j0, Bs[0], t);
    stage32x64f(Wk + k0 * 512 + j0, Bs[1], t);
    stage32x64f(Wv + k0 * 512 + j0, Bs[2], t);
    __syncthreads();
#pragma unroll 4
    for (int kk = 0; kk < 32; kk++) {
      const float4 a4 = *(const float4*)&As[kk][ty * 4];
      const float4 q4 = *(const float4*)&Bs[0][kk][tx * 4];
      const float4 k4 = *(const float4*)&Bs[1][kk][tx * 4];
      const float4 v4 = *(const float4*)&Bs[2][kk][tx * 4];
      const float a[4]  = {a4.x, a4.y, a4.z, a4.w};
      const float qr[4] = {q4.x, q4.y, q4.z, q4.w};
      const float kr[4] = {k4.x, k4.y, k4.z, k4.w};
      const float vr[4] = {v4.x, v4.y, v4.z, v4.w};
#pragma unroll
      for (int ii = 0; ii < 4; ii++)
#pragma unroll
        for (int i = 0; i < 4; i++) {
          aq[ii][i] = fmaf(a[ii], qr[i], aq[ii][i]);
          ak[ii][i] = fmaf(a[ii], kr[i], ak[ii][i]);
          av[ii][i] = fmaf(a[ii], vr[i], av[ii][i]);
        }
    }
    __syncthreads();
  }
  float bqr[4], bkr[4], bvr[4];
#pragma unroll
  for (int i = 0; i < 4; i++) {
    bqr[i] = bq[j0 + tx * 4 + i];
    bkr[i] = bk[j0 + tx * 4 + i];
    bvr[i] = bv[j0 + tx * 4 + i];
  }
#pragma unroll
  for (int ii = 0; ii < 4; ii++) {
    const int r = b * 512 + m0 + ty * 4 + ii;
    const int base = r * 512 + j0 + tx * 4;
    *(float4*)&xq[base] = make_float4(aq[ii][0] + bqr[0], aq[ii][1] + bqr[1],
                                      aq[ii][2] + bqr[2], aq[ii][3] + bqr[3]);
    *(float4*)&xk[base] = make_float4(ak[ii][0] + bkr[0], ak[ii][1] + bkr[1],
                                      ak[ii][2] + bkr[2], ak[ii][3] + bkr[3]);
    *(float4*)&xv[base] = make_float4(av[ii][0] + bvr[0], av[ii][1] + bvr[1],
                                      av[ii][2] + bvr[2], av[ii][3] + bvr[3]);
  }
}

// ---------------- fused attention v2: 8 queries/block, register-tiled GEMMs ----------------
// LDS arena A (8448 f): u_chunk[64][132] -> r1^T[64][132] -> logits[128][66]
// LDS arena B (4352 f): w1_chunk[64][68] -> w2[64][68]
#define NQ  8
#define CH  64
#define USd 132
#define LSd 66
#define WSd 68

__global__ __launch_bounds__(256) void attn_kernel(
    const float* __restrict__ p, const int* __restrict__ idx,
    const float* __restrict__ xq, const float* __restrict__ xk, const float* __restrict__ xv,
    const float* __restrict__ p1W, const float* __restrict__ p1b,
    const float* __restrict__ pbg, const float* __restrict__ pbb,
    const float* __restrict__ p2W, const float* __restrict__ p2b,
    const float* __restrict__ bn1g, const float* __restrict__ bn1b,
    const float* __restrict__ w1W, const float* __restrict__ w1b,
    const float* __restrict__ bn2g, const float* __restrict__ bn2b,
    const float* __restrict__ w2W, const float* __restrict__ w2b,
    float* __restrict__ out) {
  const float rno = 1.0f / sqrtf(1.0f + 1e-5f);
  const int b  = blockIdx.y;
  const int n0 = blockIdx.x * NQ;
  const int t  = threadIdx.x;
  __shared__ float A[8448];
  __shared__ float Bs[64 * WSd];
  __shared__ float h_s[128][3];
  __shared__ int   idx_s[128];

  if (t < 128) idx_s[t] = idx[(b * Nv + n0 + (t >> 4)) * NSv + (t & 15)] & (Nv - 1);
  __syncthreads();

  // h[row][j] = relu(bn_p(p_r @ p1W + p1b)) for 128 rows
  for (int e = t; e < 384; e += 256) {
    const int row = e / 3, j = e % 3;
    const int m = idx_s[row];
    const int n = n0 + (row >> 4);
    float d0 = p[(b * Nv + m) * 3 + 0] - p[(b * Nv + n) * 3 + 0];
    float d1 = p[(b * Nv + m) * 3 + 1] - p[(b * Nv + n) * 3 + 1];
    float d2 = p[(b * Nv + m) * 3 + 2] - p[(b * Nv + n) * 3 + 2];
    float y = d0 * p1W[0 * 3 + j] + d1 * p1W[1 * 3 + j] + d2 * p1W[2 * 3 + j] + p1b[j];
    y = y * (pbg[j] * rno) + pbb[j];
    h_s[row][j] = fmaxf(y, 0.0f);
  }
  __syncthreads();

  const int rt = t >> 4, jt = t & 15;
  const int r0 = rt * 8, j0 = jt * 4;
  float acc[8][4] = {};

  // ---- t1 = u(128x512) @ w1(512x64), chunked over c ----
  for (int kc = 0; kc < Cv; kc += CH) {
    {  // stage w1 chunk [64][64] -> Bs
      const int cl = t >> 2, seg = (t & 3) * 16;
      const float* src = w1W + (kc + cl) * 64 + seg;
      float* dst = &Bs[cl * WSd + seg];
#pragma unroll
      for (int i = 0; i < 4; i++) *(float4*)&dst[i * 4] = *(const float4*)&src[i * 4];
    }
    {  // compute u chunk, transposed: A[cl][row]
      const int row = t >> 1, ci = (t & 1) * 32;
      const int m = idx_s[row];
      const float h0 = h_s[row][0], h1 = h_s[row][1], h2 = h_s[row][2];
      const float* xkr = xk + (b * Nv + m) * Cv + kc + ci;
      const float* xqr = xq + (b * Nv + n0 + (row >> 4)) * Cv + kc + ci;
#pragma unroll
      for (int i2 = 0; i2 < 8; i2++) {
        const float4 kv = *(const float4*)&xkr[i2 * 4];
        const float4 qv = *(const float4*)&xqr[i2 * 4];
        const float kk4[4] = {kv.x, kv.y, kv.z, kv.w};
        const float qq4[4] = {qv.x, qv.y, qv.z, qv.w};
#pragma unroll
        for (int i3 = 0; i3 < 4; i3++) {
          const int c = kc + ci + i2 * 4 + i3;
          float pr = h0 * p2W[c] + h1 * p2W[512 + c] + h2 * p2W[1024 + c] + p2b[c];
          float uv = (kk4[i3] - qq4[i3] + pr) * (bn1g[c] * rno) + bn1b[c];
          A[(ci + i2 * 4 + i3) * USd + row] = fmaxf(uv, 0.0f);
        }
      }
    }
    __syncthreads();
#pragma unroll 4
    for (int cl = 0; cl < CH; cl++) {
      const float4 u0 = *(const float4*)&A[cl * USd + r0];
      const float4 u1 = *(const float4*)&A[cl * USd + r0 + 4];
      const float4 wv = *(const float4*)&Bs[cl * WSd + j0];
      const float ua[8] = {u0.x, u0.y, u0.z, u0.w, u1.x, u1.y, u1.z, u1.w};
      const float wa[4] = {wv.x, wv.y, wv.z, wv.w};
#pragma unroll
      for (int ri = 0; ri < 8; ri++)
#pragma unroll
        for (int ji = 0; ji < 4; ji++)
          acc[ri][ji] = fmaf(ua[ri], wa[ji], acc[ri][ji]);
    }
    __syncthreads();
  }

  {  // stage w2 [64][64] -> Bs
    const int cl = t >> 2, seg = (t & 3) * 16;
    const float* src = w2W + cl * 64 + seg;
    float* dst = &Bs[cl * WSd + seg];
#pragma unroll
    for (int i = 0; i < 4; i++) *(float4*)&dst[i * 4] = *(const float4*)&src[i * 4];
  }
  {  // bn2 + relu -> r1^T into A
#pragma unroll
    for (int ji = 0; ji < 4; ji++) {
      const int cc = j0 + ji;
      const float s2 = bn2g[cc] * rno, b2 = bn2b[cc], wb = w1b[cc];
#pragma unroll
      for (int ri = 0; ri < 8; ri++) {
        float v = (acc[ri][ji] + wb) * s2 + b2;
        A[cc * USd + r0 + ri] = fmaxf(v, 0.0f);
      }
    }
  }
  __syncthreads();

  // ---- t2 = r1(128x64) @ w2(64x64) ----
  float acc2[8][4] = {};
#pragma unroll 4
  for (int c = 0; c < 64; c++) {
    const float4 u0 = *(const float4*)&A[c * USd + r0];
    const float4 u1 = *(const float4*)&A[c * USd + r0 + 4];
    const float4 wv = *(const float4*)&Bs[c * WSd + j0];
    const float ua[8] = {u0.x, u0.y, u0.z, u0.w, u1.x, u1.y, u1.z, u1.w};
    const float wa[4] = {wv.x, wv.y, wv.z, wv.w};
#pragma unroll
    for (int ri = 0; ri < 8; ri++)
#pragma unroll
      for (int ji = 0; ji < 4; ji++)
        acc2[ri][ji] = fmaf(ua[ri], wa[ji], acc2[ri][ji]);
  }
  __syncthreads();
  {  // logits -> A as lg[row][jj], stride 66
#pragma unroll
    for (int ji = 0; ji < 4; ji++) {
      const float wb = w2b[j0 + ji];
#pragma unroll
      for (int ri = 0; ri < 8; ri++)
        A[(r0 + ri) * LSd + j0 + ji] = acc2[ri][ji] + wb;
    }
  }
  __syncthreads();

  // ---- softmax over the 16 neighbors, per (q, jj) ----
#pragma unroll
  for (int pp = 0; pp < 2; pp++) {
    const int pair = t + pp * 256;
    const int q = pair >> 6, jj = pair & 63;
    float* base = &A[(q * 16) * LSd + jj];
    float v[NSv];
#pragma unroll
    for (int k = 0; k < NSv; k++) v[k] = base[k * LSd];
    float mx = v[0];
#pragma unroll
    for (int k = 1; k < NSv; k++) mx = fmaxf(mx, v[k]);
    float s = 0.0f;
#pragma unroll
    for (int k = 0; k < NSv; k++) { v[k] = expf(v[k] - mx); s += v[k]; }
    const float is = 1.0f / s;
#pragma unroll
    for (int k = 0; k < NSv; k++) base[k * LSd] = v[k] * is;
  }
  __syncthreads();

  // ---- out[q][c] = sum_k (xv_g + pr) * sm[q*16+k][c&63] ----
  {
    const int q = t >> 5, cb = t & 31;
    float hk0[NSv], hk1[NSv], hk2[NSv];
    int mk[NSv];
#pragma unroll
    for (int k = 0; k < NSv; k++) {
      hk0[k] = h_s[q * 16 + k][0];
      hk1[k] = h_s[q * 16 + k][1];
      hk2[k] = h_s[q * 16 + k][2];
      mk[k]  = idx_s[q * 16 + k];
    }
    const float* smb = &A[(q * 16) * LSd];
    float* ob = out + (b * Nv + n0 + q) * Cv;
#pragma unroll 1
    for (int i = 0; i < 16; i++) {
      const int c = cb + i * 32;
      const float pa = p2W[c], pb2 = p2W[512 + c], pc = p2W[1024 + c], pd = p2b[c];
      const int jj = c & 63;
      float acco = 0.0f;
#pragma unroll
      for (int k = 0; k < NSv; k++) {
        float pr = hk0[k] * pa + hk1[k] * pb2 + hk2[k] * pc + pd;
        float val = xv[(b * Nv + mk[k]) * Cv + c] + pr;
        acco = fmaf(val, smb[k * LSd + jj], acco);
      }
      ob[c] = acco;
    }
  }
}

extern "C" void kernel_launch(void* const* d_in, const int* in_sizes, int n_in,
                              void* d_out, int out_size, void* d_ws, size_t ws_size,
                              hipStream_t stream) {
  const float* p    = (const float*)d_in[0];
  const float* x    = (const float*)d_in[1];
  const float* Wq   = (const float*)d_in[2];
  const float* bq   = (const float*)d_in[3];
  const float* Wk   = (const float*)d_in[4];
  const float* bk   = (const float*)d_in[5];
  const float* Wv   = (const float*)d_in[6];
  const float* bv   = (const float*)d_in[7];
  const float* p1W  = (const float*)d_in[8];
  const float* p1b  = (const float*)d_in[9];
  const float* pbg  = (const float*)d_in[10];
  const float* pbb  = (const float*)d_in[11];
  const float* p2W  = (const float*)d_in[12];
  const float* p2b  = (const float*)d_in[13];
  const float* bn1g = (const float*)d_in[14];
  const float* bn1b = (const float*)d_in[15];
  const float* w1W  = (const float*)d_in[16];
  const float* w1b  = (const float*)d_in[17];
  const float* bn2g = (const float*)d_in[18];
  const float* bn2b = (const float*)d_in[19];
  const float* w2W  = (const float*)d_in[20];
  const float* w2b  = (const float*)d_in[21];

  // ws layout (bytes): idx int [0, 524288) | xq/xk/xv fp32, 16 MiB each -> total ~48.5 MiB
  int*   idxb = (int*)d_ws;
  float* xq   = (float*)((char*)d_ws + 524288);
  float* xk   = xq + 8192 * 512;
  float* xv   = xk + 8192 * 512;

  knn_kernel<<<dim3(8, 16), 256, 0, stream>>>(p, idxb);
  qkv_gemm<<<dim3(128, 8), 256, 0, stream>>>(x, Wq, bq, Wk, bk, Wv, bv, xq, xk, xv);
  attn_kernel<<<dim3(Nv / NQ, Bv), 256, 0, stream>>>(p, idxb, xq, xk, xv,
                                                     p1W, p1b, pbg, pbb, p2W, p2b,
                                                     bn1g, bn1b, w1W, w1b, bn2g, bn2b,
                                                     w2W, w2b, (float*)d_out);
}

// Round 11
// 415.370 us; speedup vs baseline: 2.2875x; 1.2181x over previous
//
#include <hip/hip_runtime.h>

typedef unsigned short u16;
typedef unsigned int   u32;

#define Bv  16
#define Nv  512
#define Cv  512
#define NSv 16
#define CCv 64

typedef __attribute__((ext_vector_type(8))) short bf16x8;
typedef __attribute__((ext_vector_type(4))) float f32x4;

__device__ __forceinline__ u16 f2bf(float f) {   // RNE fp32 -> bf16
  u32 b = __float_as_uint(f);
  return (u16)((b + 0x7fffu + ((b >> 16) & 1u)) >> 16);
}
__device__ __forceinline__ u32 pack2(float lo, float hi) {
  return (u32)f2bf(lo) | ((u32)f2bf(hi) << 16);
}

// ---------------- kNN: register-resident compare-exchange top-16 (unchanged, PASS) ----------
__global__ __launch_bounds__(256) void knn_kernel(const float* __restrict__ p,
                                                  int* __restrict__ idx_out) {
#pragma clang fp contract(off)
  __shared__ float4 pnts[Nv];
  __shared__ float  ld[64][65];
  __shared__ int    li[64][65];
  const int b  = blockIdx.y;
  const int q0 = blockIdx.x * 64;
  const int t  = threadIdx.x;
  for (int e = t; e < Nv; e += 256) {
    float x = p[(b * Nv + e) * 3 + 0];
    float y = p[(b * Nv + e) * 3 + 1];
    float z = p[(b * Nv + e) * 3 + 2];
    float s = ((x * x) + (y * y)) + (z * z);
    pnts[e] = make_float4(x, y, z, s);
  }
  __syncthreads();
  {
    const int ql = t >> 2, r = t & 3;
    const float4 q = pnts[q0 + ql];
    float bd[NSv]; int bi[NSv];
#pragma unroll
    for (int i = 0; i < NSv; i++) { bd[i] = 1e30f; bi[i] = 0; }
    const int m0 = r * 128;
#pragma unroll 1
    for (int i = 0; i < 128; i++) {
      const int m = m0 + i;
      const float4 c = pnts[m];
      float dot = __builtin_fmaf(q.z, c.z, __builtin_fmaf(q.y, c.y, q.x * c.x));
      float d = (q.w + c.w) - (2.0f * dot);
      bool cm[NSv];
#pragma unroll
      for (int j = 0; j < NSv; j++) cm[j] = bd[j] > d;
#pragma unroll
      for (int j = NSv - 1; j > 0; j--) {
        bd[j] = cm[j - 1] ? bd[j - 1] : (cm[j] ? d : bd[j]);
        bi[j] = cm[j - 1] ? bi[j - 1] : (cm[j] ? m : bi[j]);
      }
      bd[0] = cm[0] ? d : bd[0];
      bi[0] = cm[0] ? m : bi[0];
    }
#pragma unroll
    for (int j = 0; j < NSv; j++) { ld[ql][r * 16 + j] = bd[j]; li[ql][r * 16 + j] = bi[j]; }
  }
  __syncthreads();
  if (t < 64) {
    float bd[NSv]; int bi[NSv];
#pragma unroll
    for (int i = 0; i < NSv; i++) { bd[i] = 1e30f; bi[i] = 0; }
#pragma unroll 1
    for (int e = 0; e < 64; e++) {
      float d = ld[t][e];
      int   m = li[t][e];
      bool cm[NSv];
#pragma unroll
      for (int j = 0; j < NSv; j++) cm[j] = bd[j] > d;
#pragma unroll
      for (int j = NSv - 1; j > 0; j--) {
        bd[j] = cm[j - 1] ? bd[j - 1] : (cm[j] ? d : bd[j]);
        bi[j] = cm[j - 1] ? bi[j - 1] : (cm[j] ? m : bi[j]);
      }
      bd[0] = cm[0] ? d : bd[0];
      bi[0] = cm[0] ? m : bi[0];
    }
    int* o = idx_out + (b * Nv + q0 + t) * NSv;
#pragma unroll
    for (int j = 0; j < NSv; j++) o[j] = bi[j];
  }
}

// ---------------- QKV via bf16 MFMA (fp32 accumulate, fp32 out) ----------------
// Tile: 128 rows x 64 cols x 3 matrices per block; K-chunks of 32 staged as bf16
// pairs in transposed LDS (row stride 20 u32 -> 16B-aligned b128 ops, 2-way-only
// read aliasing). Fragment maps per m89/m120: A/B row|col=lane&15, k=quad*8+i;
// D col=lane&15, row=quad*4+reg.
#define ASTR 20

__global__ __launch_bounds__(256) void qkv_mfma(
    const float* __restrict__ x,
    const float* __restrict__ Wq, const float* __restrict__ bq,
    const float* __restrict__ Wk, const float* __restrict__ bk,
    const float* __restrict__ Wv, const float* __restrict__ bv,
    float* __restrict__ xq, float* __restrict__ xk, float* __restrict__ xv) {
  __shared__ u32 As[128 * ASTR];
  __shared__ u32 Ws[3 * 64 * ASTR];
  const int mt  = blockIdx.x;          // 0..63: 128-row tile
  const int b   = mt >> 2;
  const int m0c = (mt & 3) * 128;      // within-batch row offset
  const int j0  = blockIdx.y * 64;
  const int t   = threadIdx.x;
  const int lane = t & 63, w = t >> 6;
  const int l15 = lane & 15, quad = lane >> 4;
  const float* xb = x + b * 512 * 512;

  f32x4 acc[4][3][2];                  // [j-strip][mat][m-strip]
#pragma unroll
  for (int a1 = 0; a1 < 4; a1++)
#pragma unroll
    for (int a2 = 0; a2 < 3; a2++)
#pragma unroll
      for (int a3 = 0; a3 < 2; a3++) acc[a1][a2][a3] = (f32x4){0.f, 0.f, 0.f, 0.f};

  for (int k0 = 0; k0 < 512; k0 += 32) {
    // stage A: threads 0..127: k-oct x 4-row group, transposed into As[m][kp]
    if (t < 128) {
      const int oct = t & 3, mg = t >> 2;
      const int m = mg * 4;
      const int kb = k0 + oct * 8;
      union { float4 v; float s[4]; } f[8];
#pragma unroll
      for (int kk = 0; kk < 8; kk++)
        f[kk].v = *(const float4*)&xb[(kb + kk) * 512 + m0c + m];
#pragma unroll
      for (int i = 0; i < 4; i++) {
        uint4 pk;
        pk.x = pack2(f[0].s[i], f[1].s[i]);
        pk.y = pack2(f[2].s[i], f[3].s[i]);
        pk.z = pack2(f[4].s[i], f[5].s[i]);
        pk.w = pack2(f[6].s[i], f[7].s[i]);
        *(uint4*)&As[(m + i) * ASTR + oct * 4] = pk;
      }
    }
    // stage W (q,k,v): threads 0..191
    if (t < 192) {
      const int mat = t >> 6, rr = t & 63;
      const int oct = rr & 3, jg = rr >> 2;
      const int j = jg * 4;
      const int kb = k0 + oct * 8;
      const float* Wm = (mat == 0) ? Wq : (mat == 1) ? Wk : Wv;
      union { float4 v; float s[4]; } f[8];
#pragma unroll
      for (int kk = 0; kk < 8; kk++)
        f[kk].v = *(const float4*)&Wm[(kb + kk) * 512 + j0 + j];
#pragma unroll
      for (int i = 0; i < 4; i++) {
        uint4 pk;
        pk.x = pack2(f[0].s[i], f[1].s[i]);
        pk.y = pack2(f[2].s[i], f[3].s[i]);
        pk.z = pack2(f[4].s[i], f[5].s[i]);
        pk.w = pack2(f[6].s[i], f[7].s[i]);
        *(uint4*)&Ws[mat * 64 * ASTR + (j + i) * ASTR + oct * 4] = pk;
      }
    }
    __syncthreads();
    // MFMA: wave w owns m-strips {2w, 2w+1} x 4 j-strips x 3 matrices
    const bf16x8 a0 = *(const bf16x8*)&As[((2 * w + 0) * 16 + l15) * ASTR + quad * 4];
    const bf16x8 a1 = *(const bf16x8*)&As[((2 * w + 1) * 16 + l15) * ASTR + quad * 4];
#pragma unroll
    for (int js = 0; js < 4; js++)
#pragma unroll
      for (int mat = 0; mat < 3; mat++) {
        const bf16x8 bfr =
            *(const bf16x8*)&Ws[mat * 64 * ASTR + (js * 16 + l15) * ASTR + quad * 4];
        acc[js][mat][0] = __builtin_amdgcn_mfma_f32_16x16x32_bf16(a0, bfr, acc[js][mat][0], 0, 0, 0);
        acc[js][mat][1] = __builtin_amdgcn_mfma_f32_16x16x32_bf16(a1, bfr, acc[js][mat][1], 0, 0, 0);
      }
    __syncthreads();
  }

  // epilogue: bias + fp32 store
  float bias[4][3];
#pragma unroll
  for (int js = 0; js < 4; js++) {
    bias[js][0] = bq[j0 + js * 16 + l15];
    bias[js][1] = bk[j0 + js * 16 + l15];
    bias[js][2] = bv[j0 + js * 16 + l15];
  }
#pragma unroll
  for (int js = 0; js < 4; js++)
#pragma unroll
    for (int mat = 0; mat < 3; mat++) {
      float* op = (mat == 0) ? xq : (mat == 1) ? xk : xv;
#pragma unroll
      for (int st = 0; st < 2; st++) {
        const int base = (b * 512 + m0c + (2 * w + st) * 16 + quad * 4) * 512 +
                         j0 + js * 16 + l15;
        const f32x4 v = acc[js][mat][st];
#pragma unroll
        for (int reg = 0; reg < 4; reg++) op[base + reg * 512] = v[reg] + bias[js][mat];
      }
    }
}

// ---------------- fused attention v2 (unchanged from round 10, PASS) ----------------
#define NQ  8
#define CH  64
#define USd 132
#define LSd 66
#define WSd 68

__global__ __launch_bounds__(256) void attn_kernel(
    const float* __restrict__ p, const int* __restrict__ idx,
    const float* __restrict__ xq, const float* __restrict__ xk, const float* __restrict__ xv,
    const float* __restrict__ p1W, const float* __restrict__ p1b,
    const float* __restrict__ pbg, const float* __restrict__ pbb,
    const float* __restrict__ p2W, const float* __restrict__ p2b,
    const float* __restrict__ bn1g, const float* __restrict__ bn1b,
    const float* __restrict__ w1W, const float* __restrict__ w1b,
    const float* __restrict__ bn2g, const float* __restrict__ bn2b,
    const float* __restrict__ w2W, const float* __restrict__ w2b,
    float* __restrict__ out) {
  const float rno = 1.0f / sqrtf(1.0f + 1e-5f);
  const int b  = blockIdx.y;
  const int n0 = blockIdx.x * NQ;
  const int t  = threadIdx.x;
  __shared__ float A[8448];
  __shared__ float Bs[64 * WSd];
  __shared__ float h_s[128][3];
  __shared__ int   idx_s[128];

  if (t < 128) idx_s[t] = idx[(b * Nv + n0 + (t >> 4)) * NSv + (t & 15)] & (Nv - 1);
  __syncthreads();

  for (int e = t; e < 384; e += 256) {
    const int row = e / 3, j = e % 3;
    const int m = idx_s[row];
    const int n = n0 + (row >> 4);
    float d0 = p[(b * Nv + m) * 3 + 0] - p[(b * Nv + n) * 3 + 0];
    float d1 = p[(b * Nv + m) * 3 + 1] - p[(b * Nv + n) * 3 + 1];
    float d2 = p[(b * Nv + m) * 3 + 2] - p[(b * Nv + n) * 3 + 2];
    float y = d0 * p1W[0 * 3 + j] + d1 * p1W[1 * 3 + j] + d2 * p1W[2 * 3 + j] + p1b[j];
    y = y * (pbg[j] * rno) + pbb[j];
    h_s[row][j] = fmaxf(y, 0.0f);
  }
  __syncthreads();

  const int rt = t >> 4, jt = t & 15;
  const int r0 = rt * 8, j0 = jt * 4;
  float acc[8][4] = {};

  for (int kc = 0; kc < Cv; kc += CH) {
    {
      const int cl = t >> 2, seg = (t & 3) * 16;
      const float* src = w1W + (kc + cl) * 64 + seg;
      float* dst = &Bs[cl * WSd + seg];
#pragma unroll
      for (int i = 0; i < 4; i++) *(float4*)&dst[i * 4] = *(const float4*)&src[i * 4];
    }
    {
      const int row = t >> 1, ci = (t & 1) * 32;
      const int m = idx_s[row];
      const float h0 = h_s[row][0], h1 = h_s[row][1], h2 = h_s[row][2];
      const float* xkr = xk + (b * Nv + m) * Cv + kc + ci;
      const float* xqr = xq + (b * Nv + n0 + (row >> 4)) * Cv + kc + ci;
#pragma unroll
      for (int i2 = 0; i2 < 8; i2++) {
        const float4 kv = *(const float4*)&xkr[i2 * 4];
        const float4 qv = *(const float4*)&xqr[i2 * 4];
        const float kk4[4] = {kv.x, kv.y, kv.z, kv.w};
        const float qq4[4] = {qv.x, qv.y, qv.z, qv.w};
#pragma unroll
        for (int i3 = 0; i3 < 4; i3++) {
          const int c = kc + ci + i2 * 4 + i3;
          float pr = h0 * p2W[c] + h1 * p2W[512 + c] + h2 * p2W[1024 + c] + p2b[c];
          float uv = (kk4[i3] - qq4[i3] + pr) * (bn1g[c] * rno) + bn1b[c];
          A[(ci + i2 * 4 + i3) * USd + row] = fmaxf(uv, 0.0f);
        }
      }
    }
    __syncthreads();
#pragma unroll 4
    for (int cl = 0; cl < CH; cl++) {
      const float4 u0 = *(const float4*)&A[cl * USd + r0];
      const float4 u1 = *(const float4*)&A[cl * USd + r0 + 4];
      const float4 wv = *(const float4*)&Bs[cl * WSd + j0];
      const float ua[8] = {u0.x, u0.y, u0.z, u0.w, u1.x, u1.y, u1.z, u1.w};
      const float wa[4] = {wv.x, wv.y, wv.z, wv.w};
#pragma unroll
      for (int ri = 0; ri < 8; ri++)
#pragma unroll
        for (int ji = 0; ji < 4; ji++)
          acc[ri][ji] = fmaf(ua[ri], wa[ji], acc[ri][ji]);
    }
    __syncthreads();
  }

  {
    const int cl = t >> 2, seg = (t & 3) * 16;
    const float* src = w2W + cl * 64 + seg;
    float* dst = &Bs[cl * WSd + seg];
#pragma unroll
    for (int i = 0; i < 4; i++) *(float4*)&dst[i * 4] = *(const float4*)&src[i * 4];
  }
  {
#pragma unroll
    for (int ji = 0; ji < 4; ji++) {
      const int cc = j0 + ji;
      const float s2 = bn2g[cc] * rno, b2 = bn2b[cc], wb = w1b[cc];
#pragma unroll
      for (int ri = 0; ri < 8; ri++) {
        float v = (acc[ri][ji] + wb) * s2 + b2;
        A[cc * USd + r0 + ri] = fmaxf(v, 0.0f);
      }
    }
  }
  __syncthreads();

  float acc2[8][4] = {};
#pragma unroll 4
  for (int c = 0; c < 64; c++) {
    const float4 u0 = *(const float4*)&A[c * USd + r0];
    const float4 u1 = *(const float4*)&A[c * USd + r0 + 4];
    const float4 wv = *(const float4*)&Bs[c * WSd + j0];
    const float ua[8] = {u0.x, u0.y, u0.z, u0.w, u1.x, u1.y, u1.z, u1.w};
    const float wa[4] = {wv.x, wv.y, wv.z, wv.w};
#pragma unroll
    for (int ri = 0; ri < 8; ri++)
#pragma unroll
      for (int ji = 0; ji < 4; ji++)
        acc2[ri][ji] = fmaf(ua[ri], wa[ji], acc2[ri][ji]);
  }
  __syncthreads();
  {
#pragma unroll
    for (int ji = 0; ji < 4; ji++) {
      const float wb = w2b[j0 + ji];
#pragma unroll
      for (int ri = 0; ri < 8; ri++)
        A[(r0 + ri) * LSd + j0 + ji] = acc2[ri][ji] + wb;
    }
  }
  __syncthreads();

#pragma unroll
  for (int pp = 0; pp < 2; pp++) {
    const int pair = t + pp * 256;
    const int q = pair >> 6, jj = pair & 63;
    float* base = &A[(q * 16) * LSd + jj];
    float v[NSv];
#pragma unroll
    for (int k = 0; k < NSv; k++) v[k] = base[k * LSd];
    float mx = v[0];
#pragma unroll
    for (int k = 1; k < NSv; k++) mx = fmaxf(mx, v[k]);
    float s = 0.0f;
#pragma unroll
    for (int k = 0; k < NSv; k++) { v[k] = expf(v[k] - mx); s += v[k]; }
    const float is = 1.0f / s;
#pragma unroll
    for (int k = 0; k < NSv; k++) base[k * LSd] = v[k] * is;
  }
  __syncthreads();

  {
    const int q = t >> 5, cb = t & 31;
    float hk0[NSv], hk1[NSv], hk2[NSv];
    int mk[NSv];
#pragma unroll
    for (int k = 0; k < NSv; k++) {
      hk0[k] = h_s[q * 16 + k][0];
      hk1[k] = h_s[q * 16 + k][1];
      hk2[k] = h_s[q * 16 + k][2];
      mk[k]  = idx_s[q * 16 + k];
    }
    const float* smb = &A[(q * 16) * LSd];
    float* ob = out + (b * Nv + n0 + q) * Cv;
#pragma unroll 1
    for (int i = 0; i < 16; i++) {
      const int c = cb + i * 32;
      const float pa = p2W[c], pb2 = p2W[512 + c], pc = p2W[1024 + c], pd = p2b[c];
      const int jj = c & 63;
      float acco = 0.0f;
#pragma unroll
      for (int k = 0; k < NSv; k++) {
        float pr = hk0[k] * pa + hk1[k] * pb2 + hk2[k] * pc + pd;
        float val = xv[(b * Nv + mk[k]) * Cv + c] + pr;
        acco = fmaf(val, smb[k * LSd + jj], acco);
      }
      ob[c] = acco;
    }
  }
}

extern "C" void kernel_launch(void* const* d_in, const int* in_sizes, int n_in,
                              void* d_out, int out_size, void* d_ws, size_t ws_size,
                              hipStream_t stream) {
  const float* p    = (const float*)d_in[0];
  const float* x    = (const float*)d_in[1];
  const float* Wq   = (const float*)d_in[2];
  const float* bq   = (const float*)d_in[3];
  const float* Wk   = (const float*)d_in[4];
  const float* bk   = (const float*)d_in[5];
  const float* Wv   = (const float*)d_in[6];
  const float* bv   = (const float*)d_in[7];
  const float* p1W  = (const float*)d_in[8];
  const float* p1b  = (const float*)d_in[9];
  const float* pbg  = (const float*)d_in[10];
  const float* pbb  = (const float*)d_in[11];
  const float* p2W  = (const float*)d_in[12];
  const float* p2b  = (const float*)d_in[13];
  const float* bn1g = (const float*)d_in[14];
  const float* bn1b = (const float*)d_in[15];
  const float* w1W  = (const float*)d_in[16];
  const float* w1b  = (const float*)d_in[17];
  const float* bn2g = (const float*)d_in[18];
  const float* bn2b = (const float*)d_in[19];
  const float* w2W  = (const float*)d_in[20];
  const float* w2b  = (const float*)d_in[21];

  // ws layout (bytes): idx int [0, 524288) | xq/xk/xv fp32, 16 MiB each -> total ~48.5 MiB
  int*   idxb = (int*)d_ws;
  float* xq   = (float*)((char*)d_ws + 524288);
  float* xk   = xq + 8192 * 512;
  float* xv   = xk + 8192 * 512;

  knn_kernel<<<dim3(8, 16), 256, 0, stream>>>(p, idxb);
  qkv_mfma<<<dim3(64, 8), 256, 0, stream>>>(x, Wq, bq, Wk, bk, Wv, bv, xq, xk, xv);
  attn_kernel<<<dim3(Nv / NQ, Bv), 256, 0, stream>>>(p, idxb, xq, xk, xv,
                                                     p1W, p1b, pbg, pbb, p2W, p2b,
                                                     bn1g, bn1b, w1W, w1b, bn2g, bn2b,
                                                     w2W, w2b, (float*)d_out);
}